// Round 1
// baseline (254.375 us; speedup 1.0000x reference)
//
#include <hip/hip_runtime.h>

// Depthwise 4x4 blur, stride 2, pad 1, on [16,256,256,256] f32 -> [16,256,128,128].
// Separable kernel k = f (x) f / 64, f=[1,3,3,1]. Two-phase tiled:
//   phase 1: horizontal filter during coalesced float4 row loads (shfl for halo) -> LDS
//   phase 2: vertical filter from LDS, float4 coalesced stores.
// Memory-bound: ~1.34 GB total HBM traffic -> ~215us roofline at 6.3 TB/s.

#define W    256   // input H=W
#define OW   128   // output H=W
#define TOY  16    // output rows per tile
#define IN_ROWS (2*TOY + 2)   // 34 input rows staged per tile

__global__ __launch_bounds__(256)
void downsample_fir_kernel(const float* __restrict__ x,
                           const float* __restrict__ kern,
                           float* __restrict__ out) {
    const int bid  = blockIdx.x;
    const int img  = bid >> 3;     // n*256 + c  (0..4095)
    const int tile = bid & 7;      // 8 row-tiles per image
    const int t    = threadIdx.x;
    const int lane = t & 63;
    const int wave = t >> 6;

    // Separable factors from the (uniform) 4x4 kernel.
    // fh[kx] = sum_ky k[ky][kx], fv[ky] = sum_kx k[ky][kx]  (exact: sum(k)==1).
    float fh[4], fv[4];
#pragma unroll
    for (int i = 0; i < 4; ++i) {
        fh[i] = kern[0*4 + i] + kern[1*4 + i] + kern[2*4 + i] + kern[3*4 + i];
        fv[i] = kern[i*4 + 0] + kern[i*4 + 1] + kern[i*4 + 2] + kern[i*4 + 3];
    }

    // H rows: one per staged input row, 128 horizontal-filtered values each.
    // Row stride 128 floats = 512 B -> phase-2 float4 reads are conflict-free.
    __shared__ float Hlds[IN_ROWS][OW];

    const float* xim = x + (size_t)img * (W * W);
    const int rowBase = tile * (2 * TOY) - 1;   // input row of LDS row 0 (pad 1)

    // ---- Phase 1: horizontal pass. One wave processes one full input row. ----
    for (int r = wave; r < IN_ROWS; r += 4) {
        const int g = rowBase + r;          // global input row (may be -1 or 256)
        float2 h;
        if (g >= 0 && g < W) {
            const float4 v = *(const float4*)(xim + (size_t)g * W + 4 * lane);
            float left  = __shfl_up(v.w, 1);    // col 4i-1
            float right = __shfl_down(v.x, 1);  // col 4i+4
            if (lane == 0)  left  = 0.f;        // zero pad col -1
            if (lane == 63) right = 0.f;        // zero pad col 256
            // H(r, 2i)   over cols 4i-1..4i+2 ; H(r, 2i+1) over cols 4i+1..4i+4
            h.x = fh[0]*left + fh[1]*v.x + fh[2]*v.y + fh[3]*v.z;
            h.y = fh[0]*v.y  + fh[1]*v.z + fh[2]*v.w + fh[3]*right;
        } else {
            h.x = 0.f; h.y = 0.f;               // zero-pad rows -1 / 256
        }
        *(float2*)&Hlds[r][2 * lane] = h;       // contiguous 8B/lane, no conflicts
    }
    __syncthreads();

    // ---- Phase 2: vertical pass. Thread -> 2 float4 outputs. ----
    const int ox0 = (t & 31) * 4;   // output col group (0..124)
    const int g0  = t >> 5;         // 0..7
    float* oim = out + (size_t)img * (OW * OW) + (size_t)tile * TOY * OW;
#pragma unroll
    for (int s = 0; s < 2; ++s) {
        const int oyp = g0 + 8 * s;     // output row within tile, 0..15
        const int rr  = 2 * oyp;        // LDS rows rr..rr+3
        const float4 h0 = *(const float4*)&Hlds[rr + 0][ox0];
        const float4 h1 = *(const float4*)&Hlds[rr + 1][ox0];
        const float4 h2 = *(const float4*)&Hlds[rr + 2][ox0];
        const float4 h3 = *(const float4*)&Hlds[rr + 3][ox0];
        float4 o;
        o.x = fv[0]*h0.x + fv[1]*h1.x + fv[2]*h2.x + fv[3]*h3.x;
        o.y = fv[0]*h0.y + fv[1]*h1.y + fv[2]*h2.y + fv[3]*h3.y;
        o.z = fv[0]*h0.z + fv[1]*h1.z + fv[2]*h2.z + fv[3]*h3.z;
        o.w = fv[0]*h0.w + fv[1]*h1.w + fv[2]*h2.w + fv[3]*h3.w;
        *(float4*)(oim + (size_t)oyp * OW + ox0) = o;  // coalesced 16B/lane
    }
}

extern "C" void kernel_launch(void* const* d_in, const int* in_sizes, int n_in,
                              void* d_out, int out_size, void* d_ws, size_t ws_size,
                              hipStream_t stream) {
    const float* x    = (const float*)d_in[0];
    const float* kern = (const float*)d_in[1];
    float* out        = (float*)d_out;

    const int nimg = in_sizes[0] / (W * W);   // 16*256 = 4096 (n,c) slices
    dim3 grid(nimg * 8);                      // 8 row-tiles per slice
    dim3 block(256);
    downsample_fir_kernel<<<grid, block, 0, stream>>>(x, kern, out);
}